// Round 6
// baseline (518.663 us; speedup 1.0000x reference)
//
#include <hip/hip_runtime.h>
#include <hip/hip_bf16.h>

#define F_IN 64
#define HID 64
#define NCLS 10
#define NG 512

// ---------------------------------------------------------------------------
// GEMM1: x (N x 64) @ Wl1 (64 x 128) -> xl1, @ Wr1 -> xr1.
__global__ void gemm1_kernel(const float* __restrict__ x,
                             const float* __restrict__ Wl,
                             const float* __restrict__ Wr,
                             float* __restrict__ xl, float* __restrict__ xr,
                             int N_) {
    __shared__ float xs[8 * 64];
    int r0 = blockIdx.x * 8;
    int t = threadIdx.x;
    for (int i = t; i < 8 * 64; i += 256) {
        int r = i >> 6;
        xs[i] = (r0 + r < N_) ? x[(long)(r0 + r) * 64 + (i & 63)] : 0.f;
    }
    __syncthreads();
    const float* W = (t < 128) ? Wl : Wr;
    int col = t & 127;
    float acc[8] = {0.f, 0.f, 0.f, 0.f, 0.f, 0.f, 0.f, 0.f};
    for (int k = 0; k < 64; ++k) {
        float w = W[k * 128 + col];
#pragma unroll
        for (int r = 0; r < 8; ++r) acc[r] += xs[r * 64 + k] * w;
    }
    float* out = (t < 128) ? xl : xr;
#pragma unroll
    for (int r = 0; r < 8; ++r)
        if (r0 + r < N_) out[(long)(r0 + r) * 128 + col] = acc[r];
}

// ---------------------------------------------------------------------------
// GEMM2: h1 (N x 128) @ Wl2 (128 x 64) -> xl2, @ Wr2 -> xr2.
__global__ void gemm2_kernel(const float* __restrict__ h1,
                             const float* __restrict__ Wl,
                             const float* __restrict__ Wr,
                             float* __restrict__ xl, float* __restrict__ xr,
                             int N_) {
    __shared__ float hs[8 * 128];
    int r0 = blockIdx.x * 8;
    int t = threadIdx.x;
    for (int i = t; i < 8 * 128; i += 128) {
        int r = i >> 7;
        hs[i] = (r0 + r < N_) ? h1[(long)(r0 + r) * 128 + (i & 127)] : 0.f;
    }
    __syncthreads();
    const float* W = (t < 64) ? Wl : Wr;
    int col = t & 63;
    float acc[8] = {0.f, 0.f, 0.f, 0.f, 0.f, 0.f, 0.f, 0.f};
    for (int k = 0; k < 128; ++k) {
        float w = W[k * 64 + col];
#pragma unroll
        for (int r = 0; r < 8; ++r) acc[r] += hs[r * 128 + k] * w;
    }
    float* out = (t < 64) ? xl : xr;
#pragma unroll
    for (int r = 0; r < 8; ++r)
        if (r0 + r < N_) out[(long)(r0 + r) * 64 + col] = acc[r];
}

// ---------------------------------------------------------------------------
// CSR build
__global__ void count_kernel(const int* __restrict__ ei, int* __restrict__ deg, int E_) {
    int e = blockIdx.x * 256 + threadIdx.x;
    if (e < E_) atomicAdd(&deg[ei[E_ + e]], 1);
}

__global__ void scan_kernel(const int* __restrict__ deg, int* __restrict__ rs,
                            int* __restrict__ cursor, int N_) {
    __shared__ int part[1024];
    int t = threadIdx.x;
    int chunk = (N_ + 1023) >> 10;
    int lo = t * chunk, hi = min(lo + chunk, N_);
    int s = 0;
    for (int i = lo; i < hi; ++i) s += deg[i];
    part[t] = s;
    __syncthreads();
    for (int off = 1; off < 1024; off <<= 1) {
        int v = (t >= off) ? part[t - off] : 0;
        __syncthreads();
        part[t] += v;
        __syncthreads();
    }
    int run = part[t] - s;  // exclusive base
    for (int i = lo; i < hi; ++i) {
        rs[i] = run;
        cursor[i] = run;
        run += deg[i];
    }
    if (t == 1023) rs[N_] = part[1023];
}

__global__ void scatter_kernel(const int* __restrict__ ei, int* __restrict__ cursor,
                               int* __restrict__ csr_src, int E_) {
    int e = blockIdx.x * 256 + threadIdx.x;
    if (e < E_) {
        int d = ei[E_ + e];
        int pos = atomicAdd(&cursor[d], 1);
        csr_src[pos] = ei[e];
    }
}

// ---------------------------------------------------------------------------
// Fused GATv2 layer 1 (H=2, C=64): one wave per (node, head).
// 4 edge-slots x 16 lanes, float4 per lane. 6-deep gather prefetch:
// issue 6 independent row gathers (24 edges) before consuming any —
// collapses the per-wave latency chain to ~1 round trip for typical nodes.
__global__ void gat1_kernel(const float* __restrict__ xl,
                            float* __restrict__ xr,   // in: xr1, out: h1
                            const float* __restrict__ att,
                            const float* __restrict__ b1,
                            const int* __restrict__ rs,
                            const int* __restrict__ csr_src,
                            int N_) {
    int wid = (int)(((long)blockIdx.x * blockDim.x + threadIdx.x) >> 6);
    int lane = threadIdx.x & 63;
    if (wid >= N_ * 2) return;
    int d = wid >> 1, h = wid & 1;
    int g = lane >> 4;        // edge slot 0..3
    int c4 = lane & 15;       // channel group
    long rowoff = (long)d * 128 + h * 64 + c4 * 4;
    const float4 xr4 = *(const float4*)(xr + rowoff);
    const float4 at4 = *(const float4*)(att + h * 64 + c4 * 4);

    int k0 = rs[d], k1 = rs[d + 1];
    int cnt = k1 - k0 + 1;    // virtual edges incl. self (slot 0)

    float4 acc = make_float4(0.f, 0.f, 0.f, 0.f);
    float den = 0.f;
    for (int c0 = 0; c0 < cnt; c0 += 64) {
        int wl = c0 + lane;
        int myidx = (wl >= 1 && wl < cnt) ? csr_src[k0 + wl - 1] : d;
        int lim = min(64, cnt - c0);
        for (int p = 0; p < lim; p += 24) {
            // --- prefetch phase: 6 independent gathers ---
            float4 a[6];
#pragma unroll
            for (int j = 0; j < 6; ++j) {
                int e = p + j * 4 + g;          // < 64 always (p<=48, e<=p+23)
                int s = (e < 64) ? __shfl(myidx, e, 64) : d;
                a[j] = *(const float4*)(xl + (long)s * 128 + h * 64 + c4 * 4);
            }
            // --- consume phase: 6 independent reduce chains ---
#pragma unroll
            for (int j = 0; j < 6; ++j) {
                float t, pj;
                t = a[j].x + xr4.x; t = (t >= 0.f) ? t : 0.2f * t; pj  = at4.x * t;
                t = a[j].y + xr4.y; t = (t >= 0.f) ? t : 0.2f * t; pj += at4.y * t;
                t = a[j].z + xr4.z; t = (t >= 0.f) ? t : 0.2f * t; pj += at4.z * t;
                t = a[j].w + xr4.w; t = (t >= 0.f) ? t : 0.2f * t; pj += at4.w * t;
                pj += __shfl_xor(pj, 1, 64);
                pj += __shfl_xor(pj, 2, 64);
                pj += __shfl_xor(pj, 4, 64);
                pj += __shfl_xor(pj, 8, 64);
                float w = (p + j * 4 + g < lim) ? __expf(pj) : 0.f;
                acc.x += w * a[j].x;
                acc.y += w * a[j].y;
                acc.z += w * a[j].z;
                acc.w += w * a[j].w;
                den += w;
            }
        }
    }
#pragma unroll
    for (int m = 16; m < 64; m <<= 1) {
        acc.x += __shfl_xor(acc.x, m, 64);
        acc.y += __shfl_xor(acc.y, m, 64);
        acc.z += __shfl_xor(acc.z, m, 64);
        acc.w += __shfl_xor(acc.w, m, 64);
        den   += __shfl_xor(den, m, 64);
    }
    if (g == 0) {
        const float4 b4 = *(const float4*)(b1 + h * 64 + c4 * 4);
        float inv = 1.f / den;
        float4 v;
        v.x = acc.x * inv + b4.x; v.x = (v.x > 0.f) ? v.x : __expf(v.x) - 1.f;
        v.y = acc.y * inv + b4.y; v.y = (v.y > 0.f) ? v.y : __expf(v.y) - 1.f;
        v.z = acc.z * inv + b4.z; v.z = (v.z > 0.f) ? v.z : __expf(v.z) - 1.f;
        v.w = acc.w * inv + b4.w; v.w = (v.w > 0.f) ? v.w : __expf(v.w) - 1.f;
        *(float4*)(xr + rowoff) = v;   // h1 in place
    }
}

// ---------------------------------------------------------------------------
// Fused GATv2 layer 2 (H=1, C=64) + bias + mean-pool. Same 6-deep prefetch.
__global__ void gat2_pool_kernel(const float* __restrict__ xl,
                                 const float* __restrict__ xr,
                                 const float* __restrict__ att,
                                 const float* __restrict__ b2,
                                 const int* __restrict__ rs,
                                 const int* __restrict__ csr_src,
                                 const int* __restrict__ batch,
                                 float* __restrict__ pooled,
                                 float* __restrict__ cnt_,
                                 int N_) {
    int d = (int)(((long)blockIdx.x * blockDim.x + threadIdx.x) >> 6);
    int lane = threadIdx.x & 63;
    if (d >= N_) return;
    int g = lane >> 4;
    int c4 = lane & 15;
    long rowoff = (long)d * 64 + c4 * 4;
    const float4 xr4 = *(const float4*)(xr + rowoff);
    const float4 at4 = *(const float4*)(att + c4 * 4);

    int k0 = rs[d], k1 = rs[d + 1];
    int cnt = k1 - k0 + 1;

    float4 acc = make_float4(0.f, 0.f, 0.f, 0.f);
    float den = 0.f;
    for (int c0 = 0; c0 < cnt; c0 += 64) {
        int wl = c0 + lane;
        int myidx = (wl >= 1 && wl < cnt) ? csr_src[k0 + wl - 1] : d;
        int lim = min(64, cnt - c0);
        for (int p = 0; p < lim; p += 24) {
            float4 a[6];
#pragma unroll
            for (int j = 0; j < 6; ++j) {
                int e = p + j * 4 + g;
                int s = (e < 64) ? __shfl(myidx, e, 64) : d;
                a[j] = *(const float4*)(xl + (long)s * 64 + c4 * 4);
            }
#pragma unroll
            for (int j = 0; j < 6; ++j) {
                float t, pj;
                t = a[j].x + xr4.x; t = (t >= 0.f) ? t : 0.2f * t; pj  = at4.x * t;
                t = a[j].y + xr4.y; t = (t >= 0.f) ? t : 0.2f * t; pj += at4.y * t;
                t = a[j].z + xr4.z; t = (t >= 0.f) ? t : 0.2f * t; pj += at4.z * t;
                t = a[j].w + xr4.w; t = (t >= 0.f) ? t : 0.2f * t; pj += at4.w * t;
                pj += __shfl_xor(pj, 1, 64);
                pj += __shfl_xor(pj, 2, 64);
                pj += __shfl_xor(pj, 4, 64);
                pj += __shfl_xor(pj, 8, 64);
                float w = (p + j * 4 + g < lim) ? __expf(pj) : 0.f;
                acc.x += w * a[j].x;
                acc.y += w * a[j].y;
                acc.z += w * a[j].z;
                acc.w += w * a[j].w;
                den += w;
            }
        }
    }
#pragma unroll
    for (int m = 16; m < 64; m <<= 1) {
        acc.x += __shfl_xor(acc.x, m, 64);
        acc.y += __shfl_xor(acc.y, m, 64);
        acc.z += __shfl_xor(acc.z, m, 64);
        acc.w += __shfl_xor(acc.w, m, 64);
        den   += __shfl_xor(den, m, 64);
    }
    const float4 b4 = *(const float4*)(b2 + c4 * 4);
    float inv = 1.f / den;
    float4 v;
    v.x = acc.x * inv + b4.x;
    v.y = acc.y * inv + b4.y;
    v.z = acc.z * inv + b4.z;
    v.w = acc.w * inv + b4.w;
    // each lane owns one distinct channel: chan = c4*4 + g
    float comp = (g == 0) ? v.x : (g == 1) ? v.y : (g == 2) ? v.z : v.w;
    int gr = batch[d];
    atomicAdd(&pooled[(long)gr * 64 + c4 * 4 + g], comp);
    if (lane == 0) atomicAdd(&cnt_[gr], 1.0f);
}

// ---------------------------------------------------------------------------
__global__ void final_kernel(const float* __restrict__ pooled,
                             const float* __restrict__ cnt,
                             const float* __restrict__ lin_w,
                             const float* __restrict__ lin_b,
                             float* __restrict__ out) {
    int tid = blockIdx.x * blockDim.x + threadIdx.x;
    if (tid >= NG * NCLS) return;
    int g = tid / NCLS;
    int k = tid % NCLS;
    float inv = 1.0f / fmaxf(cnt[g], 1.0f);
    float acc = lin_b[k];
    for (int c = 0; c < 64; ++c)
        acc += pooled[g * 64 + c] * inv * lin_w[c * NCLS + k];
    out[tid] = acc;
}

// ---------------------------------------------------------------------------
extern "C" void kernel_launch(void* const* d_in, const int* in_sizes, int n_in,
                              void* d_out, int out_size, void* d_ws, size_t ws_size,
                              hipStream_t stream) {
    const float* x     = (const float*)d_in[0];
    const int*   ei    = (const int*)d_in[1];
    const int*   batch = (const int*)d_in[2];
    const float* Wl1   = (const float*)d_in[3];
    const float* Wr1   = (const float*)d_in[4];
    const float* att1  = (const float*)d_in[5];
    const float* b1    = (const float*)d_in[6];
    const float* Wl2   = (const float*)d_in[7];
    const float* Wr2   = (const float*)d_in[8];
    const float* att2  = (const float*)d_in[9];
    const float* b2    = (const float*)d_in[10];
    const float* lin_w = (const float*)d_in[11];
    const float* lin_b = (const float*)d_in[12];
    float* out = (float*)d_out;

    const int N_ = in_sizes[0] / F_IN;   // 50000
    const int E_ = in_sizes[1] / 2;      // 800000

    // Workspace layout
    float* ws = (float*)d_ws;
    float* A = ws;                        // xl1 (N x 128); later xl2|xr2
    float* B = A + (long)N_ * 128;        // xr1 -> h1 in place
    float* pooled = B + (long)N_ * 128;   // 512 x 64
    float* cnt = pooled + NG * 64;        // 512
    int* deg     = (int*)(cnt + NG);      // N
    int* rs      = deg + N_;              // N+1
    int* cursor  = rs + N_ + 1;           // N
    int* csr_src = cursor + N_;           // E
    float* xl2 = A;
    float* xr2 = A + (long)N_ * 64;

    // --- CSR build (once; reused by both layers) ---
    hipMemsetAsync(deg, 0, (size_t)N_ * sizeof(int), stream);
    count_kernel<<<(E_ + 255) / 256, 256, 0, stream>>>(ei, deg, E_);
    scan_kernel<<<1, 1024, 0, stream>>>(deg, rs, cursor, N_);
    scatter_kernel<<<(E_ + 255) / 256, 256, 0, stream>>>(ei, cursor, csr_src, E_);

    // --- layer 1 ---
    gemm1_kernel<<<(N_ + 7) / 8, 256, 0, stream>>>(x, Wl1, Wr1, A, B, N_);
    {
        long waves = (long)N_ * 2;
        int blocks = (int)((waves * 64 + 255) / 256);
        gat1_kernel<<<blocks, 256, 0, stream>>>(A, B, att1, b1, rs, csr_src, N_);
    }

    // --- layer 2 ---
    gemm2_kernel<<<(N_ + 7) / 8, 128, 0, stream>>>(B, Wl2, Wr2, xl2, xr2, N_);
    hipMemsetAsync(pooled, 0, (size_t)(NG * 64 + NG) * sizeof(float), stream);
    {
        int blocks = (int)(((long)N_ * 64 + 255) / 256);
        gat2_pool_kernel<<<blocks, 256, 0, stream>>>(xl2, xr2, att2, b2, rs, csr_src,
                                                     batch, pooled, cnt, N_);
    }

    // --- classifier ---
    final_kernel<<<(NG * NCLS + 255) / 256, 256, 0, stream>>>(pooled, cnt, lin_w, lin_b, out);
}

// Round 7
// 390.273 us; speedup vs baseline: 1.3290x; 1.3290x over previous
//
#include <hip/hip_runtime.h>
#include <hip/hip_bf16.h>

#define F_IN 64
#define HID 64
#define NCLS 10
#define NG 512

// ---------------------------------------------------------------------------
// GEMM1: x (N x 64) @ Wl1 (64 x 128) -> xl1, @ Wr1 -> xr1.
__global__ void gemm1_kernel(const float* __restrict__ x,
                             const float* __restrict__ Wl,
                             const float* __restrict__ Wr,
                             float* __restrict__ xl, float* __restrict__ xr,
                             int N_) {
    __shared__ float xs[8 * 64];
    int r0 = blockIdx.x * 8;
    int t = threadIdx.x;
    for (int i = t; i < 8 * 64; i += 256) {
        int r = i >> 6;
        xs[i] = (r0 + r < N_) ? x[(long)(r0 + r) * 64 + (i & 63)] : 0.f;
    }
    __syncthreads();
    const float* W = (t < 128) ? Wl : Wr;
    int col = t & 127;
    float acc[8] = {0.f, 0.f, 0.f, 0.f, 0.f, 0.f, 0.f, 0.f};
    for (int k = 0; k < 64; ++k) {
        float w = W[k * 128 + col];
#pragma unroll
        for (int r = 0; r < 8; ++r) acc[r] += xs[r * 64 + k] * w;
    }
    float* out = (t < 128) ? xl : xr;
#pragma unroll
    for (int r = 0; r < 8; ++r)
        if (r0 + r < N_) out[(long)(r0 + r) * 128 + col] = acc[r];
}

// ---------------------------------------------------------------------------
// GEMM2: h1 (N x 128) @ Wl2 (128 x 64) -> xl2, @ Wr2 -> xr2.
__global__ void gemm2_kernel(const float* __restrict__ h1,
                             const float* __restrict__ Wl,
                             const float* __restrict__ Wr,
                             float* __restrict__ xl, float* __restrict__ xr,
                             int N_) {
    __shared__ float hs[8 * 128];
    int r0 = blockIdx.x * 8;
    int t = threadIdx.x;
    for (int i = t; i < 8 * 128; i += 128) {
        int r = i >> 7;
        hs[i] = (r0 + r < N_) ? h1[(long)(r0 + r) * 128 + (i & 127)] : 0.f;
    }
    __syncthreads();
    const float* W = (t < 64) ? Wl : Wr;
    int col = t & 63;
    float acc[8] = {0.f, 0.f, 0.f, 0.f, 0.f, 0.f, 0.f, 0.f};
    for (int k = 0; k < 128; ++k) {
        float w = W[k * 64 + col];
#pragma unroll
        for (int r = 0; r < 8; ++r) acc[r] += hs[r * 128 + k] * w;
    }
    float* out = (t < 64) ? xl : xr;
#pragma unroll
    for (int r = 0; r < 8; ++r)
        if (r0 + r < N_) out[(long)(r0 + r) * 64 + col] = acc[r];
}

// ---------------------------------------------------------------------------
// CSR build
__global__ void count_kernel(const int* __restrict__ ei, int* __restrict__ deg, int E_) {
    int e = blockIdx.x * 256 + threadIdx.x;
    if (e < E_) atomicAdd(&deg[ei[E_ + e]], 1);
}

__global__ void scan_kernel(const int* __restrict__ deg, int* __restrict__ rs,
                            int* __restrict__ cursor, int N_) {
    __shared__ int part[1024];
    int t = threadIdx.x;
    int chunk = (N_ + 1023) >> 10;
    int lo = t * chunk, hi = min(lo + chunk, N_);
    int s = 0;
    for (int i = lo; i < hi; ++i) s += deg[i];
    part[t] = s;
    __syncthreads();
    for (int off = 1; off < 1024; off <<= 1) {
        int v = (t >= off) ? part[t - off] : 0;
        __syncthreads();
        part[t] += v;
        __syncthreads();
    }
    int run = part[t] - s;  // exclusive base
    for (int i = lo; i < hi; ++i) {
        rs[i] = run;
        cursor[i] = run;
        run += deg[i];
    }
    if (t == 1023) rs[N_] = part[1023];
}

__global__ void scatter_kernel(const int* __restrict__ ei, int* __restrict__ cursor,
                               int* __restrict__ csr_src, int E_) {
    int e = blockIdx.x * 256 + threadIdx.x;
    if (e < E_) {
        int d = ei[E_ + e];
        int pos = atomicAdd(&cursor[d], 1);
        csr_src[pos] = ei[e];
    }
}

// ---------------------------------------------------------------------------
// Graph segment boundaries from the SORTED batch array: gstart[g] = first node
// of graph g; gstart[NG] = N. Handles empty graphs.
__global__ void gbound_kernel(const int* __restrict__ batch, int* __restrict__ gstart,
                              int N_) {
    int i = blockIdx.x * 256 + threadIdx.x;
    if (i >= N_) return;
    int bi = batch[i];
    int bprev = (i == 0) ? -1 : batch[i - 1];
    for (int g = bprev + 1; g <= bi; ++g) gstart[g] = i;
    if (i == N_ - 1)
        for (int g = bi + 1; g <= NG; ++g) gstart[g] = N_;
}

// ---------------------------------------------------------------------------
// Fused GATv2 layer 1 (H=2, C=64): one wave per (node, head).
// 4 edge-slots x 16 lanes, float4 per lane; register index-window + 2-deep
// gather pipeline. Self-loop = virtual edge 0.
__global__ void gat1_kernel(const float* __restrict__ xl,
                            float* __restrict__ xr,   // in: xr1, out: h1
                            const float* __restrict__ att,
                            const float* __restrict__ b1,
                            const int* __restrict__ rs,
                            const int* __restrict__ csr_src,
                            int N_) {
    int wid = (int)(((long)blockIdx.x * blockDim.x + threadIdx.x) >> 6);
    int lane = threadIdx.x & 63;
    if (wid >= N_ * 2) return;
    int d = wid >> 1, h = wid & 1;
    int g = lane >> 4;        // edge slot 0..3
    int c4 = lane & 15;       // channel group
    long rowoff = (long)d * 128 + h * 64 + c4 * 4;
    const float4 xr4 = *(const float4*)(xr + rowoff);
    const float4 at4 = *(const float4*)(att + h * 64 + c4 * 4);

    int k0 = rs[d], k1 = rs[d + 1];
    int cnt = k1 - k0 + 1;    // virtual edges incl. self (slot 0)

    float4 acc = make_float4(0.f, 0.f, 0.f, 0.f);
    float den = 0.f;
    for (int c0 = 0; c0 < cnt; c0 += 64) {
        int wl = c0 + lane;
        int myidx = (wl >= 1 && wl < cnt) ? csr_src[k0 + wl - 1] : d;
        int lim = min(64, cnt - c0);
        for (int p = 0; p < lim; p += 8) {
            int e0 = p + g, e1 = p + 4 + g;
            int s0 = __shfl(myidx, e0, 64);
            int s1 = __shfl(myidx, e1, 64);
            bool v0 = e0 < lim, v1 = e1 < lim;
            float4 a0 = *(const float4*)(xl + (long)s0 * 128 + h * 64 + c4 * 4);
            float4 a1 = *(const float4*)(xl + (long)s1 * 128 + h * 64 + c4 * 4);
            float t, p0, p1;
            t = a0.x + xr4.x; t = (t >= 0.f) ? t : 0.2f * t; p0  = at4.x * t;
            t = a0.y + xr4.y; t = (t >= 0.f) ? t : 0.2f * t; p0 += at4.y * t;
            t = a0.z + xr4.z; t = (t >= 0.f) ? t : 0.2f * t; p0 += at4.z * t;
            t = a0.w + xr4.w; t = (t >= 0.f) ? t : 0.2f * t; p0 += at4.w * t;
            t = a1.x + xr4.x; t = (t >= 0.f) ? t : 0.2f * t; p1  = at4.x * t;
            t = a1.y + xr4.y; t = (t >= 0.f) ? t : 0.2f * t; p1 += at4.y * t;
            t = a1.z + xr4.z; t = (t >= 0.f) ? t : 0.2f * t; p1 += at4.z * t;
            t = a1.w + xr4.w; t = (t >= 0.f) ? t : 0.2f * t; p1 += at4.w * t;
            p0 += __shfl_xor(p0, 1, 64);  p1 += __shfl_xor(p1, 1, 64);
            p0 += __shfl_xor(p0, 2, 64);  p1 += __shfl_xor(p1, 2, 64);
            p0 += __shfl_xor(p0, 4, 64);  p1 += __shfl_xor(p1, 4, 64);
            p0 += __shfl_xor(p0, 8, 64);  p1 += __shfl_xor(p1, 8, 64);
            float w0 = v0 ? __expf(p0) : 0.f;
            float w1 = v1 ? __expf(p1) : 0.f;
            acc.x += w0 * a0.x + w1 * a1.x;
            acc.y += w0 * a0.y + w1 * a1.y;
            acc.z += w0 * a0.z + w1 * a1.z;
            acc.w += w0 * a0.w + w1 * a1.w;
            den += w0 + w1;
        }
    }
#pragma unroll
    for (int m = 16; m < 64; m <<= 1) {
        acc.x += __shfl_xor(acc.x, m, 64);
        acc.y += __shfl_xor(acc.y, m, 64);
        acc.z += __shfl_xor(acc.z, m, 64);
        acc.w += __shfl_xor(acc.w, m, 64);
        den   += __shfl_xor(den, m, 64);
    }
    if (g == 0) {
        const float4 b4 = *(const float4*)(b1 + h * 64 + c4 * 4);
        float inv = 1.f / den;
        float4 v;
        v.x = acc.x * inv + b4.x; v.x = (v.x > 0.f) ? v.x : __expf(v.x) - 1.f;
        v.y = acc.y * inv + b4.y; v.y = (v.y > 0.f) ? v.y : __expf(v.y) - 1.f;
        v.z = acc.z * inv + b4.z; v.z = (v.z > 0.f) ? v.z : __expf(v.z) - 1.f;
        v.w = acc.w * inv + b4.w; v.w = (v.w > 0.f) ? v.w : __expf(v.w) - 1.f;
        *(float4*)(xr + rowoff) = v;   // h1 in place
    }
}

// ---------------------------------------------------------------------------
// Fused GATv2 layer 2 (H=1, C=64): writes h2 row (NO pooling, NO atomics).
__global__ void gat2_kernel(const float* __restrict__ xl,
                            const float* __restrict__ xr,
                            const float* __restrict__ att,
                            const float* __restrict__ b2,
                            const int* __restrict__ rs,
                            const int* __restrict__ csr_src,
                            float* __restrict__ h2,
                            int N_) {
    int d = (int)(((long)blockIdx.x * blockDim.x + threadIdx.x) >> 6);
    int lane = threadIdx.x & 63;
    if (d >= N_) return;
    int g = lane >> 4;
    int c4 = lane & 15;
    long rowoff = (long)d * 64 + c4 * 4;
    const float4 xr4 = *(const float4*)(xr + rowoff);
    const float4 at4 = *(const float4*)(att + c4 * 4);

    int k0 = rs[d], k1 = rs[d + 1];
    int cnt = k1 - k0 + 1;

    float4 acc = make_float4(0.f, 0.f, 0.f, 0.f);
    float den = 0.f;
    for (int c0 = 0; c0 < cnt; c0 += 64) {
        int wl = c0 + lane;
        int myidx = (wl >= 1 && wl < cnt) ? csr_src[k0 + wl - 1] : d;
        int lim = min(64, cnt - c0);
        for (int p = 0; p < lim; p += 8) {
            int e0 = p + g, e1 = p + 4 + g;
            int s0 = __shfl(myidx, e0, 64);
            int s1 = __shfl(myidx, e1, 64);
            bool v0 = e0 < lim, v1 = e1 < lim;
            float4 a0 = *(const float4*)(xl + (long)s0 * 64 + c4 * 4);
            float4 a1 = *(const float4*)(xl + (long)s1 * 64 + c4 * 4);
            float t, p0, p1;
            t = a0.x + xr4.x; t = (t >= 0.f) ? t : 0.2f * t; p0  = at4.x * t;
            t = a0.y + xr4.y; t = (t >= 0.f) ? t : 0.2f * t; p0 += at4.y * t;
            t = a0.z + xr4.z; t = (t >= 0.f) ? t : 0.2f * t; p0 += at4.z * t;
            t = a0.w + xr4.w; t = (t >= 0.f) ? t : 0.2f * t; p0 += at4.w * t;
            t = a1.x + xr4.x; t = (t >= 0.f) ? t : 0.2f * t; p1  = at4.x * t;
            t = a1.y + xr4.y; t = (t >= 0.f) ? t : 0.2f * t; p1 += at4.y * t;
            t = a1.z + xr4.z; t = (t >= 0.f) ? t : 0.2f * t; p1 += at4.z * t;
            t = a1.w + xr4.w; t = (t >= 0.f) ? t : 0.2f * t; p1 += at4.w * t;
            p0 += __shfl_xor(p0, 1, 64);  p1 += __shfl_xor(p1, 1, 64);
            p0 += __shfl_xor(p0, 2, 64);  p1 += __shfl_xor(p1, 2, 64);
            p0 += __shfl_xor(p0, 4, 64);  p1 += __shfl_xor(p1, 4, 64);
            p0 += __shfl_xor(p0, 8, 64);  p1 += __shfl_xor(p1, 8, 64);
            float w0 = v0 ? __expf(p0) : 0.f;
            float w1 = v1 ? __expf(p1) : 0.f;
            acc.x += w0 * a0.x + w1 * a1.x;
            acc.y += w0 * a0.y + w1 * a1.y;
            acc.z += w0 * a0.z + w1 * a1.z;
            acc.w += w0 * a0.w + w1 * a1.w;
            den += w0 + w1;
        }
    }
#pragma unroll
    for (int m = 16; m < 64; m <<= 1) {
        acc.x += __shfl_xor(acc.x, m, 64);
        acc.y += __shfl_xor(acc.y, m, 64);
        acc.z += __shfl_xor(acc.z, m, 64);
        acc.w += __shfl_xor(acc.w, m, 64);
        den   += __shfl_xor(den, m, 64);
    }
    if (g == 0) {
        const float4 b4 = *(const float4*)(b2 + c4 * 4);
        float inv = 1.f / den;
        float4 v;
        v.x = acc.x * inv + b4.x;
        v.y = acc.y * inv + b4.y;
        v.z = acc.z * inv + b4.z;
        v.w = acc.w * inv + b4.w;
        *(float4*)(h2 + rowoff) = v;
    }
}

// ---------------------------------------------------------------------------
// Segmented mean-pool over sorted batch ranges + 64x10 classifier.
// One 64-lane wave per graph; lane = channel. No atomics.
__global__ void pool_final_kernel(const float* __restrict__ h2,
                                  const int* __restrict__ gstart,
                                  const float* __restrict__ lin_w,
                                  const float* __restrict__ lin_b,
                                  float* __restrict__ out) {
    int g = blockIdx.x;
    int lane = threadIdx.x;
    int s = gstart[g], e = gstart[g + 1];
    float acc = 0.f;
    int i = s;
    for (; i + 3 < e; i += 4) {
        float v0 = h2[(long)i * 64 + lane];
        float v1 = h2[(long)(i + 1) * 64 + lane];
        float v2 = h2[(long)(i + 2) * 64 + lane];
        float v3 = h2[(long)(i + 3) * 64 + lane];
        acc += (v0 + v1) + (v2 + v3);
    }
    for (; i < e; ++i) acc += h2[(long)i * 64 + lane];
    float pc = acc / fmaxf((float)(e - s), 1.f);
    __shared__ float pl[64];
    pl[lane] = pc;
    __syncthreads();
    if (lane < NCLS) {
        float o = lin_b[lane];
#pragma unroll 8
        for (int c = 0; c < 64; ++c) o += pl[c] * lin_w[c * NCLS + lane];
        out[g * NCLS + lane] = o;
    }
}

// ---------------------------------------------------------------------------
extern "C" void kernel_launch(void* const* d_in, const int* in_sizes, int n_in,
                              void* d_out, int out_size, void* d_ws, size_t ws_size,
                              hipStream_t stream) {
    const float* x     = (const float*)d_in[0];
    const int*   ei    = (const int*)d_in[1];
    const int*   batch = (const int*)d_in[2];
    const float* Wl1   = (const float*)d_in[3];
    const float* Wr1   = (const float*)d_in[4];
    const float* att1  = (const float*)d_in[5];
    const float* b1    = (const float*)d_in[6];
    const float* Wl2   = (const float*)d_in[7];
    const float* Wr2   = (const float*)d_in[8];
    const float* att2  = (const float*)d_in[9];
    const float* b2    = (const float*)d_in[10];
    const float* lin_w = (const float*)d_in[11];
    const float* lin_b = (const float*)d_in[12];
    float* out = (float*)d_out;

    const int N_ = in_sizes[0] / F_IN;   // 50000
    const int E_ = in_sizes[1] / 2;      // 800000

    // Workspace layout
    float* ws = (float*)d_ws;
    float* A = ws;                        // xl1 (N x 128); later xl2|xr2
    float* B = A + (long)N_ * 128;        // xr1 -> h1 in place; later h2 (N x 64)
    int* deg     = (int*)(B + (long)N_ * 128);  // N
    int* rs      = deg + N_;              // N+1
    int* cursor  = rs + N_ + 1;           // N
    int* csr_src = cursor + N_;           // E
    int* gstart  = csr_src + E_;          // NG+1
    float* xl2 = A;
    float* xr2 = A + (long)N_ * 64;
    float* h2  = B;

    // --- CSR build + graph bounds (reused by both layers / pooling) ---
    hipMemsetAsync(deg, 0, (size_t)N_ * sizeof(int), stream);
    count_kernel<<<(E_ + 255) / 256, 256, 0, stream>>>(ei, deg, E_);
    gbound_kernel<<<(N_ + 255) / 256, 256, 0, stream>>>(batch, gstart, N_);
    scan_kernel<<<1, 1024, 0, stream>>>(deg, rs, cursor, N_);
    scatter_kernel<<<(E_ + 255) / 256, 256, 0, stream>>>(ei, cursor, csr_src, E_);

    // --- layer 1 ---
    gemm1_kernel<<<(N_ + 7) / 8, 256, 0, stream>>>(x, Wl1, Wr1, A, B, N_);
    {
        long waves = (long)N_ * 2;
        int blocks = (int)((waves * 64 + 255) / 256);
        gat1_kernel<<<blocks, 256, 0, stream>>>(A, B, att1, b1, rs, csr_src, N_);
    }

    // --- layer 2 ---
    gemm2_kernel<<<(N_ + 7) / 8, 128, 0, stream>>>(B, Wl2, Wr2, xl2, xr2, N_);
    {
        int blocks = (int)(((long)N_ * 64 + 255) / 256);
        gat2_kernel<<<blocks, 256, 0, stream>>>(xl2, xr2, att2, b2, rs, csr_src, h2, N_);
    }

    // --- pooling + classifier (segmented, atomic-free) ---
    pool_final_kernel<<<NG, 64, 0, stream>>>(h2, gstart, lin_w, lin_b, out);
}

// Round 8
// 296.379 us; speedup vs baseline: 1.7500x; 1.3168x over previous
//
#include <hip/hip_runtime.h>
#include <hip/hip_bf16.h>

#define F_IN 64
#define HID 64
#define NCLS 10
#define NG 512

// ---------------------------------------------------------------------------
// GEMM1: x (N x 64) @ Wl1 (64 x 128) -> xl1, @ Wr1 -> xr1.
__global__ void gemm1_kernel(const float* __restrict__ x,
                             const float* __restrict__ Wl,
                             const float* __restrict__ Wr,
                             float* __restrict__ xl, float* __restrict__ xr,
                             int N_) {
    __shared__ float xs[8 * 64];
    int r0 = blockIdx.x * 8;
    int t = threadIdx.x;
    for (int i = t; i < 8 * 64; i += 256) {
        int r = i >> 6;
        xs[i] = (r0 + r < N_) ? x[(long)(r0 + r) * 64 + (i & 63)] : 0.f;
    }
    __syncthreads();
    const float* W = (t < 128) ? Wl : Wr;
    int col = t & 127;
    float acc[8] = {0.f, 0.f, 0.f, 0.f, 0.f, 0.f, 0.f, 0.f};
    for (int k = 0; k < 64; ++k) {
        float w = W[k * 128 + col];
#pragma unroll
        for (int r = 0; r < 8; ++r) acc[r] += xs[r * 64 + k] * w;
    }
    float* out = (t < 128) ? xl : xr;
#pragma unroll
    for (int r = 0; r < 8; ++r)
        if (r0 + r < N_) out[(long)(r0 + r) * 128 + col] = acc[r];
}

// ---------------------------------------------------------------------------
// GEMM2: h1 (N x 128) @ Wl2 (128 x 64) -> xl2, @ Wr2 -> xr2.
__global__ void gemm2_kernel(const float* __restrict__ h1,
                             const float* __restrict__ Wl,
                             const float* __restrict__ Wr,
                             float* __restrict__ xl, float* __restrict__ xr,
                             int N_) {
    __shared__ float hs[8 * 128];
    int r0 = blockIdx.x * 8;
    int t = threadIdx.x;
    for (int i = t; i < 8 * 128; i += 128) {
        int r = i >> 7;
        hs[i] = (r0 + r < N_) ? h1[(long)(r0 + r) * 128 + (i & 127)] : 0.f;
    }
    __syncthreads();
    const float* W = (t < 64) ? Wl : Wr;
    int col = t & 63;
    float acc[8] = {0.f, 0.f, 0.f, 0.f, 0.f, 0.f, 0.f, 0.f};
    for (int k = 0; k < 128; ++k) {
        float w = W[k * 64 + col];
#pragma unroll
        for (int r = 0; r < 8; ++r) acc[r] += hs[r * 128 + k] * w;
    }
    float* out = (t < 64) ? xl : xr;
#pragma unroll
    for (int r = 0; r < 8; ++r)
        if (r0 + r < N_) out[(long)(r0 + r) * 64 + col] = acc[r];
}

// ---------------------------------------------------------------------------
// CSR build: count, 3-phase device-wide scan, scatter.
__global__ void count_kernel(const int* __restrict__ ei, int* __restrict__ deg, int E_) {
    int e = blockIdx.x * 256 + threadIdx.x;
    if (e < E_) atomicAdd(&deg[ei[E_ + e]], 1);
}

// Phase 1: block-local exclusive scan (256/block) + block totals.
__global__ void scan1_kernel(const int* __restrict__ deg, int* __restrict__ rs_part,
                             int* __restrict__ blksum, int N_) {
    __shared__ int tmp[256];
    int t = threadIdx.x;
    int i = blockIdx.x * 256 + t;
    int v = (i < N_) ? deg[i] : 0;
    tmp[t] = v;
    __syncthreads();
    for (int off = 1; off < 256; off <<= 1) {
        int add = (t >= off) ? tmp[t - off] : 0;
        __syncthreads();
        tmp[t] += add;
        __syncthreads();
    }
    if (i < N_) rs_part[i] = tmp[t] - v;          // exclusive within block
    if (t == 255) blksum[blockIdx.x] = tmp[255];  // block total
}

// Phase 2: exclusive scan of block totals (nblk <= 256), single block.
__global__ void scan2_kernel(int* __restrict__ blksum, int nblk) {
    __shared__ int tmp[256];
    int t = threadIdx.x;
    int v = (t < nblk) ? blksum[t] : 0;
    tmp[t] = v;
    __syncthreads();
    for (int off = 1; off < 256; off <<= 1) {
        int add = (t >= off) ? tmp[t - off] : 0;
        __syncthreads();
        tmp[t] += add;
        __syncthreads();
    }
    if (t < nblk) blksum[t] = tmp[t] - v;         // exclusive block offsets
}

// Phase 3: rs = rs_part + block offset; cursor = rs; rs[N] = E.
__global__ void scan3_kernel(const int* __restrict__ rs_part,
                             const int* __restrict__ blksum,
                             int* __restrict__ rs, int* __restrict__ cursor,
                             int N_, int E_) {
    int i = blockIdx.x * 256 + threadIdx.x;
    if (i < N_) {
        int v = rs_part[i] + blksum[blockIdx.x];
        rs[i] = v;
        cursor[i] = v;
    }
    if (i == 0) rs[N_] = E_;
}

__global__ void scatter_kernel(const int* __restrict__ ei, int* __restrict__ cursor,
                               int* __restrict__ csr_src, int E_) {
    int e = blockIdx.x * 256 + threadIdx.x;
    if (e < E_) {
        int d = ei[E_ + e];
        int pos = atomicAdd(&cursor[d], 1);
        csr_src[pos] = ei[e];
    }
}

// ---------------------------------------------------------------------------
// Graph segment boundaries from the SORTED batch array.
__global__ void gbound_kernel(const int* __restrict__ batch, int* __restrict__ gstart,
                              int N_) {
    int i = blockIdx.x * 256 + threadIdx.x;
    if (i >= N_) return;
    int bi = batch[i];
    int bprev = (i == 0) ? -1 : batch[i - 1];
    for (int g = bprev + 1; g <= bi; ++g) gstart[g] = i;
    if (i == N_ - 1)
        for (int g = bi + 1; g <= NG; ++g) gstart[g] = N_;
}

// ---------------------------------------------------------------------------
// Fused GATv2 layer 1 (H=2, C=64): one wave per (node, head).
__global__ void gat1_kernel(const float* __restrict__ xl,
                            float* __restrict__ xr,   // in: xr1, out: h1
                            const float* __restrict__ att,
                            const float* __restrict__ b1,
                            const int* __restrict__ rs,
                            const int* __restrict__ csr_src,
                            int N_) {
    int wid = (int)(((long)blockIdx.x * blockDim.x + threadIdx.x) >> 6);
    int lane = threadIdx.x & 63;
    if (wid >= N_ * 2) return;
    int d = wid >> 1, h = wid & 1;
    int g = lane >> 4;        // edge slot 0..3
    int c4 = lane & 15;       // channel group
    long rowoff = (long)d * 128 + h * 64 + c4 * 4;
    const float4 xr4 = *(const float4*)(xr + rowoff);
    const float4 at4 = *(const float4*)(att + h * 64 + c4 * 4);

    int k0 = rs[d], k1 = rs[d + 1];
    int cnt = k1 - k0 + 1;    // virtual edges incl. self (slot 0)

    float4 acc = make_float4(0.f, 0.f, 0.f, 0.f);
    float den = 0.f;
    for (int c0 = 0; c0 < cnt; c0 += 64) {
        int wl = c0 + lane;
        int myidx = (wl >= 1 && wl < cnt) ? csr_src[k0 + wl - 1] : d;
        int lim = min(64, cnt - c0);
        for (int p = 0; p < lim; p += 8) {
            int e0 = p + g, e1 = p + 4 + g;
            int s0 = __shfl(myidx, e0, 64);
            int s1 = __shfl(myidx, e1, 64);
            bool v0 = e0 < lim, v1 = e1 < lim;
            float4 a0 = *(const float4*)(xl + (long)s0 * 128 + h * 64 + c4 * 4);
            float4 a1 = *(const float4*)(xl + (long)s1 * 128 + h * 64 + c4 * 4);
            float t, p0, p1;
            t = a0.x + xr4.x; t = (t >= 0.f) ? t : 0.2f * t; p0  = at4.x * t;
            t = a0.y + xr4.y; t = (t >= 0.f) ? t : 0.2f * t; p0 += at4.y * t;
            t = a0.z + xr4.z; t = (t >= 0.f) ? t : 0.2f * t; p0 += at4.z * t;
            t = a0.w + xr4.w; t = (t >= 0.f) ? t : 0.2f * t; p0 += at4.w * t;
            t = a1.x + xr4.x; t = (t >= 0.f) ? t : 0.2f * t; p1  = at4.x * t;
            t = a1.y + xr4.y; t = (t >= 0.f) ? t : 0.2f * t; p1 += at4.y * t;
            t = a1.z + xr4.z; t = (t >= 0.f) ? t : 0.2f * t; p1 += at4.z * t;
            t = a1.w + xr4.w; t = (t >= 0.f) ? t : 0.2f * t; p1 += at4.w * t;
            p0 += __shfl_xor(p0, 1, 64);  p1 += __shfl_xor(p1, 1, 64);
            p0 += __shfl_xor(p0, 2, 64);  p1 += __shfl_xor(p1, 2, 64);
            p0 += __shfl_xor(p0, 4, 64);  p1 += __shfl_xor(p1, 4, 64);
            p0 += __shfl_xor(p0, 8, 64);  p1 += __shfl_xor(p1, 8, 64);
            float w0 = v0 ? __expf(p0) : 0.f;
            float w1 = v1 ? __expf(p1) : 0.f;
            acc.x += w0 * a0.x + w1 * a1.x;
            acc.y += w0 * a0.y + w1 * a1.y;
            acc.z += w0 * a0.z + w1 * a1.z;
            acc.w += w0 * a0.w + w1 * a1.w;
            den += w0 + w1;
        }
    }
#pragma unroll
    for (int m = 16; m < 64; m <<= 1) {
        acc.x += __shfl_xor(acc.x, m, 64);
        acc.y += __shfl_xor(acc.y, m, 64);
        acc.z += __shfl_xor(acc.z, m, 64);
        acc.w += __shfl_xor(acc.w, m, 64);
        den   += __shfl_xor(den, m, 64);
    }
    if (g == 0) {
        const float4 b4 = *(const float4*)(b1 + h * 64 + c4 * 4);
        float inv = 1.f / den;
        float4 v;
        v.x = acc.x * inv + b4.x; v.x = (v.x > 0.f) ? v.x : __expf(v.x) - 1.f;
        v.y = acc.y * inv + b4.y; v.y = (v.y > 0.f) ? v.y : __expf(v.y) - 1.f;
        v.z = acc.z * inv + b4.z; v.z = (v.z > 0.f) ? v.z : __expf(v.z) - 1.f;
        v.w = acc.w * inv + b4.w; v.w = (v.w > 0.f) ? v.w : __expf(v.w) - 1.f;
        *(float4*)(xr + rowoff) = v;   // h1 in place
    }
}

// ---------------------------------------------------------------------------
// Fused GATv2 layer 2 (H=1, C=64): writes h2 row (NO pooling, NO atomics).
__global__ void gat2_kernel(const float* __restrict__ xl,
                            const float* __restrict__ xr,
                            const float* __restrict__ att,
                            const float* __restrict__ b2,
                            const int* __restrict__ rs,
                            const int* __restrict__ csr_src,
                            float* __restrict__ h2,
                            int N_) {
    int d = (int)(((long)blockIdx.x * blockDim.x + threadIdx.x) >> 6);
    int lane = threadIdx.x & 63;
    if (d >= N_) return;
    int g = lane >> 4;
    int c4 = lane & 15;
    long rowoff = (long)d * 64 + c4 * 4;
    const float4 xr4 = *(const float4*)(xr + rowoff);
    const float4 at4 = *(const float4*)(att + c4 * 4);

    int k0 = rs[d], k1 = rs[d + 1];
    int cnt = k1 - k0 + 1;

    float4 acc = make_float4(0.f, 0.f, 0.f, 0.f);
    float den = 0.f;
    for (int c0 = 0; c0 < cnt; c0 += 64) {
        int wl = c0 + lane;
        int myidx = (wl >= 1 && wl < cnt) ? csr_src[k0 + wl - 1] : d;
        int lim = min(64, cnt - c0);
        for (int p = 0; p < lim; p += 8) {
            int e0 = p + g, e1 = p + 4 + g;
            int s0 = __shfl(myidx, e0, 64);
            int s1 = __shfl(myidx, e1, 64);
            bool v0 = e0 < lim, v1 = e1 < lim;
            float4 a0 = *(const float4*)(xl + (long)s0 * 64 + c4 * 4);
            float4 a1 = *(const float4*)(xl + (long)s1 * 64 + c4 * 4);
            float t, p0, p1;
            t = a0.x + xr4.x; t = (t >= 0.f) ? t : 0.2f * t; p0  = at4.x * t;
            t = a0.y + xr4.y; t = (t >= 0.f) ? t : 0.2f * t; p0 += at4.y * t;
            t = a0.z + xr4.z; t = (t >= 0.f) ? t : 0.2f * t; p0 += at4.z * t;
            t = a0.w + xr4.w; t = (t >= 0.f) ? t : 0.2f * t; p0 += at4.w * t;
            t = a1.x + xr4.x; t = (t >= 0.f) ? t : 0.2f * t; p1  = at4.x * t;
            t = a1.y + xr4.y; t = (t >= 0.f) ? t : 0.2f * t; p1 += at4.y * t;
            t = a1.z + xr4.z; t = (t >= 0.f) ? t : 0.2f * t; p1 += at4.z * t;
            t = a1.w + xr4.w; t = (t >= 0.f) ? t : 0.2f * t; p1 += at4.w * t;
            p0 += __shfl_xor(p0, 1, 64);  p1 += __shfl_xor(p1, 1, 64);
            p0 += __shfl_xor(p0, 2, 64);  p1 += __shfl_xor(p1, 2, 64);
            p0 += __shfl_xor(p0, 4, 64);  p1 += __shfl_xor(p1, 4, 64);
            p0 += __shfl_xor(p0, 8, 64);  p1 += __shfl_xor(p1, 8, 64);
            float w0 = v0 ? __expf(p0) : 0.f;
            float w1 = v1 ? __expf(p1) : 0.f;
            acc.x += w0 * a0.x + w1 * a1.x;
            acc.y += w0 * a0.y + w1 * a1.y;
            acc.z += w0 * a0.z + w1 * a1.z;
            acc.w += w0 * a0.w + w1 * a1.w;
            den += w0 + w1;
        }
    }
#pragma unroll
    for (int m = 16; m < 64; m <<= 1) {
        acc.x += __shfl_xor(acc.x, m, 64);
        acc.y += __shfl_xor(acc.y, m, 64);
        acc.z += __shfl_xor(acc.z, m, 64);
        acc.w += __shfl_xor(acc.w, m, 64);
        den   += __shfl_xor(den, m, 64);
    }
    if (g == 0) {
        const float4 b4 = *(const float4*)(b2 + c4 * 4);
        float inv = 1.f / den;
        float4 v;
        v.x = acc.x * inv + b4.x;
        v.y = acc.y * inv + b4.y;
        v.z = acc.z * inv + b4.z;
        v.w = acc.w * inv + b4.w;
        *(float4*)(h2 + rowoff) = v;
    }
}

// ---------------------------------------------------------------------------
// Segmented mean-pool over sorted batch ranges + 64x10 classifier.
__global__ void pool_final_kernel(const float* __restrict__ h2,
                                  const int* __restrict__ gstart,
                                  const float* __restrict__ lin_w,
                                  const float* __restrict__ lin_b,
                                  float* __restrict__ out) {
    int g = blockIdx.x;
    int lane = threadIdx.x;
    int s = gstart[g], e = gstart[g + 1];
    float acc = 0.f;
    int i = s;
    for (; i + 3 < e; i += 4) {
        float v0 = h2[(long)i * 64 + lane];
        float v1 = h2[(long)(i + 1) * 64 + lane];
        float v2 = h2[(long)(i + 2) * 64 + lane];
        float v3 = h2[(long)(i + 3) * 64 + lane];
        acc += (v0 + v1) + (v2 + v3);
    }
    for (; i < e; ++i) acc += h2[(long)i * 64 + lane];
    float pc = acc / fmaxf((float)(e - s), 1.f);
    __shared__ float pl[64];
    pl[lane] = pc;
    __syncthreads();
    if (lane < NCLS) {
        float o = lin_b[lane];
#pragma unroll 8
        for (int c = 0; c < 64; ++c) o += pl[c] * lin_w[c * NCLS + lane];
        out[g * NCLS + lane] = o;
    }
}

// ---------------------------------------------------------------------------
extern "C" void kernel_launch(void* const* d_in, const int* in_sizes, int n_in,
                              void* d_out, int out_size, void* d_ws, size_t ws_size,
                              hipStream_t stream) {
    const float* x     = (const float*)d_in[0];
    const int*   ei    = (const int*)d_in[1];
    const int*   batch = (const int*)d_in[2];
    const float* Wl1   = (const float*)d_in[3];
    const float* Wr1   = (const float*)d_in[4];
    const float* att1  = (const float*)d_in[5];
    const float* b1    = (const float*)d_in[6];
    const float* Wl2   = (const float*)d_in[7];
    const float* Wr2   = (const float*)d_in[8];
    const float* att2  = (const float*)d_in[9];
    const float* b2    = (const float*)d_in[10];
    const float* lin_w = (const float*)d_in[11];
    const float* lin_b = (const float*)d_in[12];
    float* out = (float*)d_out;

    const int N_ = in_sizes[0] / F_IN;   // 50000
    const int E_ = in_sizes[1] / 2;      // 800000

    // Workspace layout
    float* ws = (float*)d_ws;
    float* A = ws;                        // xl1 (N x 128); later xl2|xr2
    float* B = A + (long)N_ * 128;        // xr1 -> h1 in place; later h2 (N x 64)
    int* deg     = (int*)(B + (long)N_ * 128);  // N
    int* rs      = deg + N_;              // N+1
    int* cursor  = rs + N_ + 1;           // N
    int* csr_src = cursor + N_;           // E
    int* gstart  = csr_src + E_;          // NG+1
    int* rs_part = gstart + NG + 1;       // N
    int* blksum  = rs_part + N_;          // 256
    float* xl2 = A;
    float* xr2 = A + (long)N_ * 64;
    float* h2  = B;

    const int nblk = (N_ + 255) / 256;   // 196 for N=50000 (must be <= 256)

    // --- CSR build + graph bounds ---
    hipMemsetAsync(deg, 0, (size_t)N_ * sizeof(int), stream);
    count_kernel<<<(E_ + 255) / 256, 256, 0, stream>>>(ei, deg, E_);
    gbound_kernel<<<(N_ + 255) / 256, 256, 0, stream>>>(batch, gstart, N_);
    scan1_kernel<<<nblk, 256, 0, stream>>>(deg, rs_part, blksum, N_);
    scan2_kernel<<<1, 256, 0, stream>>>(blksum, nblk);
    scan3_kernel<<<nblk, 256, 0, stream>>>(rs_part, blksum, rs, cursor, N_, E_);
    scatter_kernel<<<(E_ + 255) / 256, 256, 0, stream>>>(ei, cursor, csr_src, E_);

    // --- layer 1 ---
    gemm1_kernel<<<(N_ + 7) / 8, 256, 0, stream>>>(x, Wl1, Wr1, A, B, N_);
    {
        long waves = (long)N_ * 2;
        int blocks = (int)((waves * 64 + 255) / 256);
        gat1_kernel<<<blocks, 256, 0, stream>>>(A, B, att1, b1, rs, csr_src, N_);
    }

    // --- layer 2 ---
    gemm2_kernel<<<(N_ + 7) / 8, 128, 0, stream>>>(B, Wl2, Wr2, xl2, xr2, N_);
    {
        int blocks = (int)(((long)N_ * 64 + 255) / 256);
        gat2_kernel<<<blocks, 256, 0, stream>>>(xl2, xr2, att2, b2, rs, csr_src, h2, N_);
    }

    // --- pooling + classifier (segmented, atomic-free) ---
    pool_final_kernel<<<NG, 64, 0, stream>>>(h2, gstart, lin_w, lin_b, out);
}